// Round 6
// baseline (3551.827 us; speedup 1.0000x reference)
//
#include <hip/hip_runtime.h>

// GRU-D fused scan, v8: MFMA, 4 waves, full register headroom.
// R10 diagnosis: v7's 8440 cyc/step was serial latency — the "+a" pins
// consumed the 256-reg (2 waves/EU) budget, leaving ~88 VGPRs, so only
// ~2-3 B-frags could be in flight; each ds_read_b128 (~120cyc) serialized
// against its MFMAs, plus copy churn around pinned frags. TLP can't help:
// wall time = 1024 x one block's step chain.
// Fix: NT=256 (4 waves, waves_per_eu(1,1) -> 512-reg budget). Wave owns 32
// units (two 16-row tiles): A 336dw + C 64 + B-in-flight ~48 + temps fits
// 512 with NO pins (RA uses AV class; MFMA reads AGPRs free). B-frags read
// once, reused by both tiles (40KB LDS/step). L0 r/z/n-input biases folded
// into Wih0 col k=34 (x[34]=1). Zero-quad shared for acc init.
// Skew (unchanged from v7, verified): step i computes h0(i) (from h0(i-1),
// x(i)) and h1(i-1) (from h0(i-1), h1(i-2)). One barrier/step.

#define NBLK 16
#define BS 16
#define SS 1024
#define DD 32
#define HH 128
#define NT 256
#define XSTR 72      // x row stride in f16 (64 data+pad; k=34 is bias-1 col)
#define HSTR 136     // h row stride in f16

typedef _Float16 f16;
typedef __attribute__((ext_vector_type(8))) _Float16 h8;
typedef __attribute__((ext_vector_type(2))) _Float16 h2;
typedef __attribute__((ext_vector_type(4))) float f4;

__device__ inline f4 mfma16(h8 a, h8 b, f4 c) {
    return __builtin_amdgcn_mfma_f32_16x16x32_f16(a, b, c, 0, 0, 0);
}
__device__ inline float frcp(float x) { return __builtin_amdgcn_rcpf(x); }
__device__ inline float fast_sigm(float x) { return frcp(1.0f + __expf(-x)); }
__device__ inline float fast_tanh(float x) {
    x = fminf(15.0f, fmaxf(-15.0f, x));
    float e = __expf(-2.0f * x);
    return (1.0f - e) * frcp(1.0f + e);
}

__global__
__attribute__((amdgpu_flat_work_group_size(NT, NT), amdgpu_waves_per_eu(1, 1)))
void gru_fused(
    const float* __restrict__ t_in, const float* __restrict__ x_in,
    const float* __restrict__ Wih0, const float* __restrict__ Whh0,
    const float* __restrict__ bih0, const float* __restrict__ bhh0,
    const float* __restrict__ Wih1, const float* __restrict__ Whh1,
    const float* __restrict__ bih1, const float* __restrict__ bhh1,
    float* __restrict__ out, char* __restrict__ ws)
{
    __shared__ float tb[SS];                          // 4 KB
    __shared__ __align__(16) f16 xb[2][BS][XSTR];     // 4.5 KB
    __shared__ __align__(16) f16 h0b[2][BS][HSTR];    // 8.5 KB
    __shared__ __align__(16) f16 h1b[2][BS][HSTR];    // 8.5 KB

    const int tid = threadIdx.x;
    const int w   = tid >> 6;          // wave 0..3: units [32w, 32w+32)
    const int l   = tid & 63;
    const int cb  = l & 15;            // MFMA col = batch
    const int g   = l >> 4;            // k-group / C row-group
    const int blk = blockIdx.x;

    // ---- A-frags: [tile][gate q][ks]; lane row = q*128 + 32w+16t+(l&15) ----
    h8 axf[2][3][2], ah0f[2][3][4], ax1f[2][3][4], ah1f[2][3][4];
    #pragma unroll
    for (int t = 0; t < 2; t++) {
        const int arow = 32 * w + 16 * t + (l & 15);
        #pragma unroll
        for (int q = 0; q < 3; q++) {
            const int row = q * 128 + arow;
            #pragma unroll
            for (int ks = 0; ks < 2; ks++) {
                h8 f;
                #pragma unroll
                for (int e = 0; e < 8; e++) {
                    int k = 32 * ks + 8 * g + e;
                    float v;
                    if (k < 34)       v = Wih0[row * 34 + k];
                    else if (k == 34) v = (q < 2) ? (bih0[row] + bhh0[row])
                                                  : bih0[row];   // n: input bias
                    else              v = 0.0f;
                    f[e] = (f16)v;
                }
                axf[t][q][ks] = f;
            }
            #pragma unroll
            for (int ks = 0; ks < 4; ks++) {
                h8 f0, f1, f2;
                #pragma unroll
                for (int e = 0; e < 8; e++) {
                    int k = 32 * ks + 8 * g + e;
                    f0[e] = (f16)Whh0[row * 128 + k];
                    f1[e] = (f16)Wih1[row * 128 + k];
                    f2[e] = (f16)Whh1[row * 128 + k];
                }
                ah0f[t][q][ks] = f0; ax1f[t][q][ks] = f1; ah1f[t][q][ks] = f2;
            }
        }
    }

    // ---- packed biases (f16): L0 n-hidden; L1 r/z combined, n in/hidden ----
    h2 bnh0[2][2], brz1[2][4], bn1[2][4];
    #pragma unroll
    for (int t = 0; t < 2; t++)
        #pragma unroll
        for (int e = 0; e < 4; e++) {
            const int j = 32 * w + 16 * t + 4 * g + e;
            if ((e & 1) == 0)
                bnh0[t][e >> 1] = h2{(f16)bhh0[j + 256], (f16)bhh0[j + 1 + 256]};
            brz1[t][e] = h2{(f16)(bih1[j] + bhh1[j]),
                            (f16)(bih1[j + 128] + bhh1[j + 128])};
            bn1[t][e]  = h2{(f16)bih1[j + 256], (f16)bhh1[j + 256]};
        }

    // ---- persistent h state (lane-local, C layout: row 4g+e, col cb) ----
    float hr0[2][4] = {{0.f,0.f,0.f,0.f},{0.f,0.f,0.f,0.f}};
    float hr1[2][4] = {{0.f,0.f,0.f,0.f},{0.f,0.f,0.f,0.f}};

    // ---- imputation: lane handles batch ib, features fx and fx+16 ----
    const int ib = 4 * w + g;          // 4 waves x 4 groups = 16 batches
    const int fx = l & 15;
    const float* xptr = x_in + ((size_t)(blk * BS + ib) * SS) * DD;
    float xp0 = 0.0f, xp1 = 0.0f, tprev = 0.0f; bool hasprev = false;

    auto impute = [&](int i, float xa, float xc, int wb) {
        bool nanp = (xa != xa) || (xc != xc);
        unsigned long long bal = __ballot(nanp);
        bool m = ((bal >> (16 * g)) & 0xFFFFull) != 0ull;
        float ia = m ? xp0 : xa;
        float ic = m ? xp1 : xc;
        xb[wb][ib][fx]      = (f16)ia;
        xb[wb][ib][fx + 16] = (f16)ic;
        if (!m) { xp0 = xa; xp1 = xc; }
        float tcur = tb[i];
        float tdel = (i == 0) ? 0.0f : (tcur - tb[i - 1]);
        float texp = hasprev ? (tcur - tprev) : tdel;
        if (fx == 0) {
            h2 mt = { (f16)(m ? 1.0f : 0.0f), (f16)texp };
            *(h2*)&xb[wb][ib][32] = mt;
        }
        if (!m) { hasprev = true; tprev = tcur; }
    };

    // ---- prologue: tb, zero panels, bias-1 col, impute(0) ----
    for (int idx = tid; idx < SS; idx += NT) tb[idx] = t_in[idx];
    {
        int* z0 = (int*)&h0b[0][0][0];
        for (int idx = tid; idx < 2 * BS * HSTR / 2; idx += NT) z0[idx] = 0;
        int* z1 = (int*)&h1b[0][0][0];
        for (int idx = tid; idx < 2 * BS * HSTR / 2; idx += NT) z1[idx] = 0;
        int* z2 = (int*)&xb[0][0][0];
        for (int idx = tid; idx < 2 * BS * XSTR / 2; idx += NT) z2[idx] = 0;
    }
    __syncthreads();
    if (tid < 32) xb[tid >> 4][tid & 15][34] = (f16)1.0f;   // bias-1 column
    {
        float xa0 = xptr[fx], xc0 = xptr[fx + 16];
        impute(0, xa0, xc0, 0);
    }
    __syncthreads();

    const f4 z4 = {0.f, 0.f, 0.f, 0.f};

    for (int i = 0; i <= SS; ++i) {
        const int pi = i & 1;
        const bool doL0 = (i < SS), doL1 = (i > 0), doImp = (i + 1 < SS);

        // early global prefetch for next imputation
        float xa_n = 0.0f, xc_n = 0.0f;
        if (doImp) {
            const float* xr = xptr + (size_t)(i + 1) * DD;
            xa_n = xr[fx]; xc_n = xr[fx + 16];
        }

        const f16* bx  = &xb [pi    ][cb][0];   // x(i) + bias col
        const f16* bh0 = &h0b[pi ^ 1][cb][0];   // h0(i-1)
        const f16* bh1 = &h1b[pi    ][cb][0];   // h1(i-2)

        // B-frags: x first, then h0, then h1 (each reused by both tiles)
        h8 BX0 = *(const h8*)(bx + 8 * g);
        h8 BX1 = *(const h8*)(bx + 32 + 8 * g);
        h8 BH0[4], BH1[4];
        #pragma unroll
        for (int ks = 0; ks < 4; ks++) BH0[ks] = *(const h8*)(bh0 + 32 * ks + 8 * g);

        f4 aR0[2], aZ0[2], aX0[2], aH0[2], aR1[2], aZ1[2], aX1[2], aH1[2];

        // x phase: gx0 (+ folded biases) -> L0 {r,z,ngx}
        #pragma unroll
        for (int t = 0; t < 2; t++) {
            aR0[t] = mfma16(axf[t][0][0], BX0, z4);
            aZ0[t] = mfma16(axf[t][1][0], BX0, z4);
            aX0[t] = mfma16(axf[t][2][0], BX0, z4);
            aR0[t] = mfma16(axf[t][0][1], BX1, aR0[t]);
            aZ0[t] = mfma16(axf[t][1][1], BX1, aZ0[t]);
            aX0[t] = mfma16(axf[t][2][1], BX1, aX0[t]);
        }
        #pragma unroll
        for (int ks = 0; ks < 4; ks++) BH1[ks] = *(const h8*)(bh1 + 32 * ks + 8 * g);

        // h0 phase: gh0 -> L0 {r,z,ngh}; gx1 -> L1 {r,z,ngx}
        #pragma unroll
        for (int t = 0; t < 2; t++) {
            aH0[t] = mfma16(ah0f[t][2][0], BH0[0], z4);
            aR1[t] = mfma16(ax1f[t][0][0], BH0[0], z4);
            aZ1[t] = mfma16(ax1f[t][1][0], BH0[0], z4);
            aX1[t] = mfma16(ax1f[t][2][0], BH0[0], z4);
            aR0[t] = mfma16(ah0f[t][0][0], BH0[0], aR0[t]);
            aZ0[t] = mfma16(ah0f[t][1][0], BH0[0], aZ0[t]);
            #pragma unroll
            for (int ks = 1; ks < 4; ks++) {
                aR0[t] = mfma16(ah0f[t][0][ks], BH0[ks], aR0[t]);
                aZ0[t] = mfma16(ah0f[t][1][ks], BH0[ks], aZ0[t]);
                aH0[t] = mfma16(ah0f[t][2][ks], BH0[ks], aH0[t]);
                aR1[t] = mfma16(ax1f[t][0][ks], BH0[ks], aR1[t]);
                aZ1[t] = mfma16(ax1f[t][1][ks], BH0[ks], aZ1[t]);
                aX1[t] = mfma16(ax1f[t][2][ks], BH0[ks], aX1[t]);
            }
        }
        // h1 phase: gh1 -> L1 {r,z,ngh}
        #pragma unroll
        for (int t = 0; t < 2; t++) {
            aH1[t] = mfma16(ah1f[t][2][0], BH1[0], z4);
            aR1[t] = mfma16(ah1f[t][0][0], BH1[0], aR1[t]);
            aZ1[t] = mfma16(ah1f[t][1][0], BH1[0], aZ1[t]);
            #pragma unroll
            for (int ks = 1; ks < 4; ks++) {
                aR1[t] = mfma16(ah1f[t][0][ks], BH1[ks], aR1[t]);
                aZ1[t] = mfma16(ah1f[t][1][ks], BH1[ks], aZ1[t]);
                aH1[t] = mfma16(ah1f[t][2][ks], BH1[ks], aH1[t]);
            }
        }

        // imputation for step i+1 (different buffer than this step's reads)
        if (doImp) impute(i + 1, xa_n, xc_n, pi ^ 1);

        // ---- lane-local gate updates (row j = 32w+16t+4g+e, batch cb) ----
        if (doL0) {
            #pragma unroll
            for (int t = 0; t < 2; t++) {
                #pragma unroll
                for (int e = 0; e < 4; e++) {
                    float rr = fast_sigm(aR0[t][e]);            // biases folded
                    float zz = fast_sigm(aZ0[t][e]);
                    float nn = fast_tanh(aX0[t][e]
                               + rr * (aH0[t][e] + (float)bnh0[t][e >> 1][e & 1]));
                    hr0[t][e] = nn + zz * (hr0[t][e] - nn);
                }
                union { h2 h[2]; int2 d; } up;
                up.h[0] = h2{(f16)hr0[t][0], (f16)hr0[t][1]};
                up.h[1] = h2{(f16)hr0[t][2], (f16)hr0[t][3]};
                *(int2*)&h0b[pi][cb][32 * w + 16 * t + 4 * g] = up.d;   // h0(i)
            }
        }
        if (doL1) {
            #pragma unroll
            for (int t = 0; t < 2; t++) {
                #pragma unroll
                for (int e = 0; e < 4; e++) {
                    float rr = fast_sigm(aR1[t][e] + (float)brz1[t][e][0]);
                    float zz = fast_sigm(aZ1[t][e] + (float)brz1[t][e][1]);
                    float nn = fast_tanh(aX1[t][e] + (float)bn1[t][e][0]
                               + rr * (aH1[t][e] + (float)bn1[t][e][1]));
                    hr1[t][e] = nn + zz * (hr1[t][e] - nn);
                }
                union { h2 h[2]; int2 d; } up;
                up.h[0] = h2{(f16)hr1[t][0], (f16)hr1[t][1]};
                up.h[1] = h2{(f16)hr1[t][2], (f16)hr1[t][3]};
                *(int2*)&h1b[pi ^ 1][cb][32 * w + 16 * t + 4 * g] = up.d; // h1(i-1)
            }
        }
        __syncthreads();   // h0(i), h1(i-1), x(i+1) visible for next step
    }

    // hr1 = h1(SS-1): final hidden of layer 1
    #pragma unroll
    for (int t = 0; t < 2; t++) {
        float* op = out + (size_t)(blk * BS + cb) * HH + 32 * w + 16 * t + 4 * g;
        *(float4*)op = make_float4(hr1[t][0], hr1[t][1], hr1[t][2], hr1[t][3]);
    }
}

extern "C" void kernel_launch(void* const* d_in, const int* in_sizes, int n_in,
                              void* d_out, int out_size, void* d_ws, size_t ws_size,
                              hipStream_t stream) {
    gru_fused<<<dim3(NBLK), dim3(NT), 0, stream>>>(
        (const float*)d_in[0], (const float*)d_in[1],
        (const float*)d_in[2], (const float*)d_in[3],
        (const float*)d_in[4], (const float*)d_in[5],
        (const float*)d_in[6], (const float*)d_in[7],
        (const float*)d_in[8], (const float*)d_in[9],
        (float*)d_out, (char*)d_ws);
}